// Round 1
// baseline (115.604 us; speedup 1.0000x reference)
//
#include <hip/hip_runtime.h>
#include <hip/hip_bf16.h>

// MultiLinear: y[b,g,o] = sum_i x[b,g,i] * W[g,o,i] + bias[g,o]
// B=4096, G=16, DIN=512, DOUT=512, all fp32 in/out.
// Strategy: bf16 MFMA (16x16x32) with in-kernel fp32->bf16 conversion during
// LDS staging. 128x128 tile, BK=64, 4 waves (2x2), padded LDS to kill bank
// conflicts. Fused bias in epilogue.

#define BATCH 4096
#define NGRP  16
#define DIN   512
#define DOUT  512

#define BM 128
#define BN 128
#define BK 64
#define LDK 72   // padded inner dim in bf16 elems (64 + 8) -> row stride 144 B

typedef __bf16 bf16x8 __attribute__((ext_vector_type(8)));
typedef float  f32x4  __attribute__((ext_vector_type(4)));

__global__ __launch_bounds__(256, 2)
void MultiLinear_48498770706571_kernel(const float* __restrict__ X,
                                       const float* __restrict__ Wt,
                                       const float* __restrict__ Bias,
                                       float* __restrict__ Y) {
    const int bid = blockIdx.x;
    const int g   = bid >> 7;          // 128 tiles per group (32 m x 4 n)
    const int mt  = (bid >> 2) & 31;
    const int nt  = bid & 3;
    const int bm0 = mt * BM;
    const int bn0 = nt * BN;

    __shared__ __bf16 As[BM][LDK];
    __shared__ __bf16 Bs[BN][LDK];

    const int tid  = threadIdx.x;
    const int lane = tid & 63;
    const int w    = tid >> 6;        // wave id 0..3
    const int wm   = (w >> 1) * 64;   // wave row offset in tile
    const int wn   = (w & 1) * 64;    // wave col offset in tile

    // staging: 8 floats (32 B) per thread per pass; 8 threads/row; 32 rows/pass
    const int srow = tid >> 3;        // 0..31
    const int scol = (tid & 7) * 8;   // 0,8,...,56

    f32x4 acc[4][4];
#pragma unroll
    for (int i = 0; i < 4; ++i)
#pragma unroll
        for (int j = 0; j < 4; ++j) acc[i][j] = f32x4{0.f, 0.f, 0.f, 0.f};

    const float* xbase = X + (size_t)bm0 * (NGRP * DIN) + g * DIN;
    const float* wbase = Wt + (size_t)g * (DOUT * DIN) + (size_t)bn0 * DIN;

    for (int kt = 0; kt < DIN / BK; ++kt) {
        const int k0 = kt * BK;
        f32x4 ra[4][2], rb[4][2];
#pragma unroll
        for (int p = 0; p < 4; ++p) {
            const int row = p * 32 + srow;
            const float* pa = xbase + (size_t)row * (NGRP * DIN) + k0 + scol;
            ra[p][0] = *(const f32x4*)pa;
            ra[p][1] = *(const f32x4*)(pa + 4);
            const float* pb = wbase + (size_t)row * DIN + k0 + scol;
            rb[p][0] = *(const f32x4*)pb;
            rb[p][1] = *(const f32x4*)(pb + 4);
        }
        __syncthreads();   // previous compute done reading LDS
#pragma unroll
        for (int p = 0; p < 4; ++p) {
            const int row = p * 32 + srow;
            bf16x8 va, vb;
#pragma unroll
            for (int j = 0; j < 4; ++j) {
                va[j]     = (__bf16)ra[p][0][j];
                va[j + 4] = (__bf16)ra[p][1][j];
                vb[j]     = (__bf16)rb[p][0][j];
                vb[j + 4] = (__bf16)rb[p][1][j];
            }
            *(bf16x8*)&As[row][scol] = va;
            *(bf16x8*)&Bs[row][scol] = vb;
        }
        __syncthreads();
        // compute this K-step: 2 sub-K of 32, 16 MFMAs each
#pragma unroll
        for (int kk = 0; kk < BK; kk += 32) {
            const int ko = kk + (lane >> 4) * 8;
            bf16x8 af[4], bfr[4];
#pragma unroll
            for (int mi = 0; mi < 4; ++mi)
                af[mi] = *(const bf16x8*)&As[wm + mi * 16 + (lane & 15)][ko];
#pragma unroll
            for (int ni = 0; ni < 4; ++ni)
                bfr[ni] = *(const bf16x8*)&Bs[wn + ni * 16 + (lane & 15)][ko];
#pragma unroll
            for (int mi = 0; mi < 4; ++mi)
#pragma unroll
                for (int ni = 0; ni < 4; ++ni)
                    acc[mi][ni] = __builtin_amdgcn_mfma_f32_16x16x32_bf16(
                        af[mi], bfr[ni], acc[mi][ni], 0, 0, 0);
        }
    }

    // epilogue: C/D layout col = lane&15, row = (lane>>4)*4 + j
    const int r0 = (lane >> 4) * 4;
    const int c  = lane & 15;
    float bias_n[4];
#pragma unroll
    for (int ni = 0; ni < 4; ++ni)
        bias_n[ni] = Bias[g * DOUT + bn0 + wn + ni * 16 + c];
#pragma unroll
    for (int mi = 0; mi < 4; ++mi) {
#pragma unroll
        for (int j = 0; j < 4; ++j) {
            const int row = bm0 + wm + mi * 16 + r0 + j;
            float* yrow = Y + (size_t)row * (NGRP * DOUT) + g * DOUT + bn0 + wn;
#pragma unroll
            for (int ni = 0; ni < 4; ++ni)
                yrow[ni * 16 + c] = acc[mi][ni][j] + bias_n[ni];
        }
    }
}

extern "C" void kernel_launch(void* const* d_in, const int* in_sizes, int n_in,
                              void* d_out, int out_size, void* d_ws, size_t ws_size,
                              hipStream_t stream) {
    const float* X    = (const float*)d_in[0];
    const float* Wt   = (const float*)d_in[1];
    const float* Bias = (const float*)d_in[2];
    float* Y          = (float*)d_out;

    const int grid = NGRP * (BATCH / BM) * (DOUT / BN);  // 16*32*4 = 2048
    MultiLinear_48498770706571_kernel<<<grid, 256, 0, stream>>>(X, Wt, Bias, Y);
}

// Round 2
// 111.367 us; speedup vs baseline: 1.0380x; 1.0380x over previous
//
#include <hip/hip_runtime.h>
#include <hip/hip_bf16.h>

// MultiLinear: y[b,g,o] = sum_i x[b,g,i] * W[g,o,i] + bias[g,o]
// B=4096, G=16, DIN=512, DOUT=512, all fp32 in/out.
// bf16 MFMA (16x16x32) with fp32->bf16 conversion during LDS staging.
// 128x128 tile, BK=64, 4 waves. R2: async-STAGE split (prefetch next K-step's
// global loads before compute so HBM latency hides under MFMA) + chunked
// XCD-aware blockIdx swizzle for L2 locality.

#define BATCH 4096
#define NGRP  16
#define DIN   512
#define DOUT  512

#define BM 128
#define BN 128
#define BK 64
#define NT (DIN / BK)   // 8 K-steps
#define LDK 72          // padded inner dim (bf16 elems): 144 B row stride

typedef __bf16 bf16x8 __attribute__((ext_vector_type(8)));
typedef float  f32x4  __attribute__((ext_vector_type(4)));

__global__ __launch_bounds__(256, 2)
void MultiLinear_48498770706571_kernel(const float* __restrict__ X,
                                       const float* __restrict__ Wt,
                                       const float* __restrict__ Bias,
                                       float* __restrict__ Y) {
    // XCD-aware chunked swizzle: 2048 blocks, 8 XCDs, 256 consecutive tiles
    // per XCD (= 2 full groups: W working set 2 MB fits the 4 MB XCD L2).
    const int bid = (blockIdx.x & 7) * (gridDim.x >> 3) + (blockIdx.x >> 3);
    const int g   = bid >> 7;          // 128 tiles per group (32 m x 4 n)
    const int mt  = (bid >> 2) & 31;
    const int nt  = bid & 3;
    const int bm0 = mt * BM;
    const int bn0 = nt * BN;

    __shared__ __bf16 As[BM][LDK];
    __shared__ __bf16 Bs[BN][LDK];

    const int tid  = threadIdx.x;
    const int lane = tid & 63;
    const int w    = tid >> 6;        // wave id 0..3
    const int wm   = (w >> 1) * 64;   // wave row offset in tile
    const int wn   = (w & 1) * 64;    // wave col offset in tile

    // staging: 8 floats (32 B) per thread per pass; 8 threads/row; 32 rows/pass
    const int srow = tid >> 3;        // 0..31
    const int scol = (tid & 7) * 8;   // 0,8,...,56

    f32x4 acc[4][4];
#pragma unroll
    for (int i = 0; i < 4; ++i)
#pragma unroll
        for (int j = 0; j < 4; ++j) acc[i][j] = f32x4{0.f, 0.f, 0.f, 0.f};

    // per-thread staging base pointers (row fixed per p)
    const float* pA[4];
    const float* pB[4];
#pragma unroll
    for (int p = 0; p < 4; ++p) {
        const int row = p * 32 + srow;
        pA[p] = X + (size_t)(bm0 + row) * (NGRP * DIN) + g * DIN + scol;
        pB[p] = Wt + (size_t)g * (DOUT * DIN) + (size_t)(bn0 + row) * DIN + scol;
    }

    f32x4 ra[4][2], rb[4][2];
    // prologue: issue loads for kt=0
#pragma unroll
    for (int p = 0; p < 4; ++p) {
        ra[p][0] = *(const f32x4*)(pA[p]);
        ra[p][1] = *(const f32x4*)(pA[p] + 4);
        rb[p][0] = *(const f32x4*)(pB[p]);
        rb[p][1] = *(const f32x4*)(pB[p] + 4);
    }

    for (int kt = 0; kt < NT; ++kt) {
        __syncthreads();   // previous compute done reading LDS
        // convert + write current K-step to LDS (implicit vmcnt wait on data)
#pragma unroll
        for (int p = 0; p < 4; ++p) {
            const int row = p * 32 + srow;
            bf16x8 va, vb;
#pragma unroll
            for (int j = 0; j < 4; ++j) {
                va[j]     = (__bf16)ra[p][0][j];
                va[j + 4] = (__bf16)ra[p][1][j];
                vb[j]     = (__bf16)rb[p][0][j];
                vb[j + 4] = (__bf16)rb[p][1][j];
            }
            *(bf16x8*)&As[row][scol] = va;
            *(bf16x8*)&Bs[row][scol] = vb;
        }
        // async-STAGE: issue NEXT K-step's loads now, before compute,
        // so HBM latency hides under the MFMA + ds_read phase below.
        if (kt + 1 < NT) {
            const int k0 = (kt + 1) * BK;
#pragma unroll
            for (int p = 0; p < 4; ++p) {
                ra[p][0] = *(const f32x4*)(pA[p] + k0);
                ra[p][1] = *(const f32x4*)(pA[p] + k0 + 4);
                rb[p][0] = *(const f32x4*)(pB[p] + k0);
                rb[p][1] = *(const f32x4*)(pB[p] + k0 + 4);
            }
        }
        __syncthreads();
        // compute this K-step: 2 sub-K of 32, 16 MFMAs each
#pragma unroll
        for (int kk = 0; kk < BK; kk += 32) {
            const int ko = kk + (lane >> 4) * 8;
            bf16x8 af[4], bfr[4];
#pragma unroll
            for (int mi = 0; mi < 4; ++mi)
                af[mi] = *(const bf16x8*)&As[wm + mi * 16 + (lane & 15)][ko];
#pragma unroll
            for (int ni = 0; ni < 4; ++ni)
                bfr[ni] = *(const bf16x8*)&Bs[wn + ni * 16 + (lane & 15)][ko];
#pragma unroll
            for (int mi = 0; mi < 4; ++mi)
#pragma unroll
                for (int ni = 0; ni < 4; ++ni)
                    acc[mi][ni] = __builtin_amdgcn_mfma_f32_16x16x32_bf16(
                        af[mi], bfr[ni], acc[mi][ni], 0, 0, 0);
        }
    }

    // epilogue: C/D layout col = lane&15, row = (lane>>4)*4 + j
    const int r0 = (lane >> 4) * 4;
    const int c  = lane & 15;
    float bias_n[4];
#pragma unroll
    for (int ni = 0; ni < 4; ++ni)
        bias_n[ni] = Bias[g * DOUT + bn0 + wn + ni * 16 + c];
#pragma unroll
    for (int mi = 0; mi < 4; ++mi) {
#pragma unroll
        for (int j = 0; j < 4; ++j) {
            const int row = bm0 + wm + mi * 16 + r0 + j;
            float* yrow = Y + (size_t)row * (NGRP * DOUT) + g * DOUT + bn0 + wn;
#pragma unroll
            for (int ni = 0; ni < 4; ++ni)
                yrow[ni * 16 + c] = acc[mi][ni][j] + bias_n[ni];
        }
    }
}

extern "C" void kernel_launch(void* const* d_in, const int* in_sizes, int n_in,
                              void* d_out, int out_size, void* d_ws, size_t ws_size,
                              hipStream_t stream) {
    const float* X    = (const float*)d_in[0];
    const float* Wt   = (const float*)d_in[1];
    const float* Bias = (const float*)d_in[2];
    float* Y          = (float*)d_out;

    const int grid = NGRP * (BATCH / BM) * (DOUT / BN);  // 16*32*4 = 2048
    MultiLinear_48498770706571_kernel<<<grid, 256, 0, stream>>>(X, Wt, Bias, Y);
}

// Round 3
// 109.338 us; speedup vs baseline: 1.0573x; 1.0186x over previous
//
#include <hip/hip_runtime.h>
#include <hip/hip_bf16.h>

// MultiLinear: y[b,g,o] = sum_i x[b,g,i] * W[g,o,i] + bias[g,o]
// B=4096, G=16, DIN=512, DOUT=512, fp32 in/out.
// R3: 8-wave block (512 thr), 128x128 tile, BK=64, double-buffered LDS with
// ONE raw s_barrier per K-step (no __syncthreads -> no vmcnt(0) drain), reg
// prefetch of next K-step held live across the barrier. bf16 MFMA 16x16x32,
// fp32->bf16 cvt at stage time. XCD-chunked blockIdx swizzle.

#define BATCH 4096
#define NGRP  16
#define DIN   512
#define DOUT  512

#define BM 128
#define BN 128
#define BK 64
#define NT (DIN / BK)   // 8 K-steps
#define LDK 72          // padded: 144 B row stride (multiple of 16 B)

typedef __bf16 bf16x8 __attribute__((ext_vector_type(8)));
typedef float  f32x4  __attribute__((ext_vector_type(4)));

__global__ __launch_bounds__(512, 4)
void MultiLinear_48498770706571_kernel(const float* __restrict__ X,
                                       const float* __restrict__ Wt,
                                       const float* __restrict__ Bias,
                                       float* __restrict__ Y) {
    // XCD-chunked swizzle: 2048 blocks / 8 XCDs = 256 consecutive tiles each.
    const int bid = (blockIdx.x & 7) * 256 + (blockIdx.x >> 3);
    const int g   = bid >> 7;          // 128 tiles per group (32 m x 4 n)
    const int mt  = (bid >> 2) & 31;
    const int nt  = bid & 3;
    const int bm0 = mt * BM;
    const int bn0 = nt * BN;

    __shared__ __bf16 As[2][BM][LDK];
    __shared__ __bf16 Bs[2][BN][LDK];

    const int tid  = threadIdx.x;
    const int lane = tid & 63;
    const int w    = tid >> 6;        // 0..7
    const int wm   = (w >> 2) * 64;   // {0,64}
    const int wn   = (w & 3) * 32;    // {0,32,64,96}

    // staging: each thread owns one row-segment: 16 consecutive floats
    const int srow = tid >> 2;        // 0..127
    const int scol = (tid & 3) * 16;  // 0,16,32,48

    const float* pA = X + (size_t)(bm0 + srow) * (NGRP * DIN) + g * DIN + scol;
    const float* pB = Wt + (size_t)g * (DOUT * DIN) + (size_t)(bn0 + srow) * DIN + scol;

    f32x4 ra[4], rb[4];   // 16 floats A + 16 floats B in flight

#define ISSUE_LOADS(k0)                                                    \
    do {                                                                   \
        const f32x4* qa = (const f32x4*)(pA + (k0));                       \
        const f32x4* qb = (const f32x4*)(pB + (k0));                       \
        ra[0] = qa[0]; ra[1] = qa[1]; ra[2] = qa[2]; ra[3] = qa[3];        \
        rb[0] = qb[0]; rb[1] = qb[1]; rb[2] = qb[2]; rb[3] = qb[3];        \
    } while (0)

#define CVT_WRITE(buf)                                                     \
    do {                                                                   \
        bf16x8 va0, va1, vb0, vb1;                                         \
        _Pragma("unroll")                                                  \
        for (int j = 0; j < 4; ++j) {                                      \
            va0[j] = (__bf16)ra[0][j]; va0[j + 4] = (__bf16)ra[1][j];      \
            va1[j] = (__bf16)ra[2][j]; va1[j + 4] = (__bf16)ra[3][j];      \
            vb0[j] = (__bf16)rb[0][j]; vb0[j + 4] = (__bf16)rb[1][j];      \
            vb1[j] = (__bf16)rb[2][j]; vb1[j + 4] = (__bf16)rb[3][j];      \
        }                                                                  \
        *(bf16x8*)&As[buf][srow][scol]     = va0;                          \
        *(bf16x8*)&As[buf][srow][scol + 8] = va1;                          \
        *(bf16x8*)&Bs[buf][srow][scol]     = vb0;                          \
        *(bf16x8*)&Bs[buf][srow][scol + 8] = vb1;                          \
    } while (0)

    f32x4 acc[4][2];
#pragma unroll
    for (int mi = 0; mi < 4; ++mi)
#pragma unroll
        for (int ni = 0; ni < 2; ++ni) acc[mi][ni] = f32x4{0.f, 0.f, 0.f, 0.f};

    // prologue: stage kt=0 (one-time exposed vmcnt wait)
    ISSUE_LOADS(0);
    CVT_WRITE(0);

    for (int kt = 0; kt < NT; ++kt) {
        // issue next K-step's global loads BEFORE the barrier; raw barrier
        // (not __syncthreads) so they stay in flight across it.
        if (kt + 1 < NT) ISSUE_LOADS((kt + 1) * BK);
        // drain own ds ops (write visibility + read anti-dep), then barrier.
        asm volatile("s_waitcnt lgkmcnt(0)" ::: "memory");
        __builtin_amdgcn_s_barrier();

        const int cur = kt & 1;
#pragma unroll
        for (int kk = 0; kk < BK; kk += 32) {
            const int ko = kk + (lane >> 4) * 8;
            bf16x8 af[4], bfr[2];
#pragma unroll
            for (int mi = 0; mi < 4; ++mi)
                af[mi] = *(const bf16x8*)&As[cur][wm + mi * 16 + (lane & 15)][ko];
#pragma unroll
            for (int ni = 0; ni < 2; ++ni)
                bfr[ni] = *(const bf16x8*)&Bs[cur][wn + ni * 16 + (lane & 15)][ko];
#pragma unroll
            for (int mi = 0; mi < 4; ++mi)
#pragma unroll
                for (int ni = 0; ni < 2; ++ni)
                    acc[mi][ni] = __builtin_amdgcn_mfma_f32_16x16x32_bf16(
                        af[mi], bfr[ni], acc[mi][ni], 0, 0, 0);
        }
        // convert + write NEXT K-step into the other buffer (vmcnt wait here,
        // hidden under the compute above). Safe: buf^1 reads finished by all
        // waves before the barrier above (lgkmcnt(0) drained them).
        if (kt + 1 < NT) CVT_WRITE((kt + 1) & 1);
    }

    // epilogue: C/D layout col = lane&15, row = (lane>>4)*4 + j  (verified R1)
    const int r0 = (lane >> 4) * 4;
    const int c  = lane & 15;
    float bias_n[2];
#pragma unroll
    for (int ni = 0; ni < 2; ++ni)
        bias_n[ni] = Bias[g * DOUT + bn0 + wn + ni * 16 + c];
#pragma unroll
    for (int mi = 0; mi < 4; ++mi) {
#pragma unroll
        for (int j = 0; j < 4; ++j) {
            const int row = bm0 + wm + mi * 16 + r0 + j;
            float* yrow = Y + (size_t)row * (NGRP * DOUT) + g * DOUT + bn0 + wn;
#pragma unroll
            for (int ni = 0; ni < 2; ++ni)
                yrow[ni * 16 + c] = acc[mi][ni][j] + bias_n[ni];
        }
    }
#undef ISSUE_LOADS
#undef CVT_WRITE
}

extern "C" void kernel_launch(void* const* d_in, const int* in_sizes, int n_in,
                              void* d_out, int out_size, void* d_ws, size_t ws_size,
                              hipStream_t stream) {
    const float* X    = (const float*)d_in[0];
    const float* Wt   = (const float*)d_in[1];
    const float* Bias = (const float*)d_in[2];
    float* Y          = (float*)d_out;

    const int grid = NGRP * (BATCH / BM) * (DOUT / BN);  // 2048
    MultiLinear_48498770706571_kernel<<<grid, 512, 0, stream>>>(X, Wt, Bias, Y);
}

// Round 4
// 90.525 us; speedup vs baseline: 1.2770x; 1.2078x over previous
//
#include <hip/hip_runtime.h>
#include <hip/hip_bf16.h>

// MultiLinear: y[b,g,o] = sum_i x[b,g,i] * W[g,o,i] + bias[g,o]
// B=4096, G=16, DIN=512, DOUT=512, fp32 in/out.
// R4: 256x256 tile (halves global-staging bytes per MFMA — the dominant pipe
// per R3 analysis), 8 waves / 512 threads, per-wave 128x64 (acc[8][4]),
// double-buffered LDS (144 KB), one raw s_barrier per K-step, reg prefetch
// of next K-step held live across the barrier (R3-verified schedule).
// bf16 MFMA 16x16x32, fp32->bf16 cvt at stage time. XCD-chunked swizzle.

#define BATCH 4096
#define NGRP  16
#define DIN   512
#define DOUT  512

#define BM 256
#define BN 256
#define BK 64
#define NT (DIN / BK)   // 8 K-steps
#define LDK 72          // padded: 144 B row stride (multiple of 16 B)

typedef __bf16 bf16x8 __attribute__((ext_vector_type(8)));
typedef float  f32x4  __attribute__((ext_vector_type(4)));

__global__ __launch_bounds__(512, 2)
void MultiLinear_48498770706571_kernel(const float* __restrict__ X,
                                       const float* __restrict__ Wt,
                                       const float* __restrict__ Bias,
                                       float* __restrict__ Y) {
    // 512 blocks / 8 XCDs = 64 consecutive tiles (2 full groups) per XCD.
    const int bid = (blockIdx.x & 7) * 64 + (blockIdx.x >> 3);
    const int g   = bid >> 5;          // 32 tiles per group (16 m x 2 n)
    const int mt  = (bid >> 1) & 15;
    const int nt  = bid & 1;
    const int bm0 = mt * BM;
    const int bn0 = nt * BN;

    __shared__ __bf16 As[2][BM][LDK];
    __shared__ __bf16 Bs[2][BN][LDK];

    const int tid  = threadIdx.x;
    const int lane = tid & 63;
    const int w    = tid >> 6;        // 0..7
    const int wm   = (w >> 2) * 128;  // {0,128}
    const int wn   = (w & 3) * 64;    // {0,64,128,192}

    // staging: 512 threads cover 128 rows/pass (4 threads/row, 16 floats each),
    // 2 passes for 256 rows. Per K-step per thread: 8 f32x4 A + 8 f32x4 B.
    const int srow = tid >> 2;        // 0..127
    const int scol = (tid & 3) * 16;  // 0,16,32,48

    const float* pA = X + (size_t)(bm0 + srow) * (NGRP * DIN) + g * DIN + scol;
    const float* pB = Wt + (size_t)g * (DOUT * DIN) + (size_t)(bn0 + srow) * DIN + scol;
    const size_t strideA = (size_t)128 * (NGRP * DIN);  // pass-1 row offset
    const size_t strideB = (size_t)128 * DIN;

    f32x4 ra[2][4], rb[2][4];   // 64 VGPRs in flight

#define ISSUE_LOADS(k0)                                                    \
    do {                                                                   \
        const f32x4* qa0 = (const f32x4*)(pA + (k0));                      \
        const f32x4* qa1 = (const f32x4*)(pA + strideA + (k0));            \
        const f32x4* qb0 = (const f32x4*)(pB + (k0));                      \
        const f32x4* qb1 = (const f32x4*)(pB + strideB + (k0));            \
        ra[0][0] = qa0[0]; ra[0][1] = qa0[1]; ra[0][2] = qa0[2]; ra[0][3] = qa0[3]; \
        ra[1][0] = qa1[0]; ra[1][1] = qa1[1]; ra[1][2] = qa1[2]; ra[1][3] = qa1[3]; \
        rb[0][0] = qb0[0]; rb[0][1] = qb0[1]; rb[0][2] = qb0[2]; rb[0][3] = qb0[3]; \
        rb[1][0] = qb1[0]; rb[1][1] = qb1[1]; rb[1][2] = qb1[2]; rb[1][3] = qb1[3]; \
    } while (0)

#define CVT_WRITE(buf)                                                     \
    do {                                                                   \
        _Pragma("unroll")                                                  \
        for (int p = 0; p < 2; ++p) {                                      \
            bf16x8 v0, v1, u0, u1;                                         \
            _Pragma("unroll")                                              \
            for (int j = 0; j < 4; ++j) {                                  \
                v0[j] = (__bf16)ra[p][0][j]; v0[j + 4] = (__bf16)ra[p][1][j]; \
                v1[j] = (__bf16)ra[p][2][j]; v1[j + 4] = (__bf16)ra[p][3][j]; \
                u0[j] = (__bf16)rb[p][0][j]; u0[j + 4] = (__bf16)rb[p][1][j]; \
                u1[j] = (__bf16)rb[p][2][j]; u1[j + 4] = (__bf16)rb[p][3][j]; \
            }                                                              \
            const int row = p * 128 + srow;                                \
            *(bf16x8*)&As[buf][row][scol]     = v0;                        \
            *(bf16x8*)&As[buf][row][scol + 8] = v1;                        \
            *(bf16x8*)&Bs[buf][row][scol]     = u0;                        \
            *(bf16x8*)&Bs[buf][row][scol + 8] = u1;                        \
        }                                                                  \
    } while (0)

    f32x4 acc[8][4];
#pragma unroll
    for (int mi = 0; mi < 8; ++mi)
#pragma unroll
        for (int ni = 0; ni < 4; ++ni) acc[mi][ni] = f32x4{0.f, 0.f, 0.f, 0.f};

    // prologue: stage kt=0 (one-time exposed vmcnt wait)
    ISSUE_LOADS(0);
    CVT_WRITE(0);

    for (int kt = 0; kt < NT; ++kt) {
        // prefetch next K-step before the barrier; raw barrier (no vmcnt drain)
        if (kt + 1 < NT) ISSUE_LOADS((kt + 1) * BK);
        asm volatile("s_waitcnt lgkmcnt(0)" ::: "memory");
        __builtin_amdgcn_s_barrier();

        const int cur = kt & 1;
#pragma unroll
        for (int kk = 0; kk < BK; kk += 32) {
            const int ko = kk + (lane >> 4) * 8;
            bf16x8 af[8], bfr[4];
#pragma unroll
            for (int mi = 0; mi < 8; ++mi)
                af[mi] = *(const bf16x8*)&As[cur][wm + mi * 16 + (lane & 15)][ko];
#pragma unroll
            for (int ni = 0; ni < 4; ++ni)
                bfr[ni] = *(const bf16x8*)&Bs[cur][wn + ni * 16 + (lane & 15)][ko];
#pragma unroll
            for (int mi = 0; mi < 8; ++mi)
#pragma unroll
                for (int ni = 0; ni < 4; ++ni)
                    acc[mi][ni] = __builtin_amdgcn_mfma_f32_16x16x32_bf16(
                        af[mi], bfr[ni], acc[mi][ni], 0, 0, 0);
        }
        // convert + write NEXT K-step into the other buffer (vmcnt waits here,
        // hidden under the compute above).
        if (kt + 1 < NT) CVT_WRITE((kt + 1) & 1);
    }

    // epilogue: C/D layout col = lane&15, row = (lane>>4)*4 + j  (verified R1)
    const int r0 = (lane >> 4) * 4;
    const int c  = lane & 15;
    float bias_n[4];
#pragma unroll
    for (int ni = 0; ni < 4; ++ni)
        bias_n[ni] = Bias[g * DOUT + bn0 + wn + ni * 16 + c];
#pragma unroll
    for (int mi = 0; mi < 8; ++mi) {
#pragma unroll
        for (int j = 0; j < 4; ++j) {
            const int row = bm0 + wm + mi * 16 + r0 + j;
            float* yrow = Y + (size_t)row * (NGRP * DOUT) + g * DOUT + bn0 + wn;
#pragma unroll
            for (int ni = 0; ni < 4; ++ni)
                yrow[ni * 16 + c] = acc[mi][ni][j] + bias_n[ni];
        }
    }
#undef ISSUE_LOADS
#undef CVT_WRITE
}

extern "C" void kernel_launch(void* const* d_in, const int* in_sizes, int n_in,
                              void* d_out, int out_size, void* d_ws, size_t ws_size,
                              hipStream_t stream) {
    const float* X    = (const float*)d_in[0];
    const float* Wt   = (const float*)d_in[1];
    const float* Bias = (const float*)d_in[2];
    float* Y          = (float*)d_out;

    const int grid = NGRP * (BATCH / BM) * (DOUT / BN);  // 16*16*2 = 512
    MultiLinear_48498770706571_kernel<<<grid, 512, 0, stream>>>(X, Wt, Bias, Y);
}